// Round 17
// baseline (209.042 us; speedup 1.0000x reference)
//
#include <hip/hip_runtime.h>
#include <math.h>

typedef unsigned short ushort_t;
typedef __attribute__((ext_vector_type(8))) short short8v;
typedef __attribute__((ext_vector_type(4))) float float4v;

#define BB 2
#define NN 2048
#define HH 16
#define DHH 64
#define DIMM 1024
#define QKV3 3072
#define INNERR 1024
// 0.125 * log2(e): fold attention scale + base-2 exp into Q
#define QSCALE 0.1803368801111244f

__device__ __forceinline__ ushort_t f2bf(float f) {
    unsigned u = __float_as_uint(f);
    u += 0x7fffu + ((u >> 16) & 1u);  // round to nearest even
    return (ushort_t)(u >> 16);
}
__device__ __forceinline__ float bf2f(unsigned h) {
    return __uint_as_float(h << 16);
}
__device__ __forceinline__ unsigned pk_bf16(float a, float b) {
#if __has_builtin(__builtin_amdgcn_cvt_pk_bf16_f32)
    typedef __attribute__((ext_vector_type(2))) __bf16 bf16x2;
    bf16x2 r = __builtin_amdgcn_cvt_pk_bf16_f32(a, b);
    return __builtin_bit_cast(unsigned, r);
#else
    return (unsigned)f2bf(a) | ((unsigned)f2bf(b) << 16);
#endif
}
// bare v_exp_f32 -- OCML exp2f carries denorm/overflow guards we don't need
__device__ __forceinline__ float fast_exp2(float x) {
#if __has_builtin(__builtin_amdgcn_exp2f)
    return __builtin_amdgcn_exp2f(x);
#else
    return exp2f(x);
#endif
}
__device__ __forceinline__ void gl2lds16(const void* g, void* l) {
    __builtin_amdgcn_global_load_lds(
        (const __attribute__((address_space(1))) unsigned int*)g,
        (__attribute__((address_space(3))) unsigned int*)l, 16, 0, 0);
}

// One kernel converts x (4096 blks), w_qkv (3072), w_out (1024) to bf16.
__global__ __launch_bounds__(256) void conv_fused(const float* __restrict__ x,
                                                  const float* __restrict__ wqkv,
                                                  const float* __restrict__ wout,
                                                  ushort_t* __restrict__ xo,
                                                  ushort_t* __restrict__ wqkvo,
                                                  ushort_t* __restrict__ wouto) {
    int blk = blockIdx.x;
    const float* in; ushort_t* out; int i;
    if (blk < 4096)      { in = x;    out = xo;    i = blk * 256 + threadIdx.x; }
    else if (blk < 7168) { in = wqkv; out = wqkvo; i = (blk - 4096) * 256 + threadIdx.x; }
    else                 { in = wout; out = wouto; i = (blk - 7168) * 256 + threadIdx.x; }
    float4 v = ((const float4*)in)[i];
    ushort4 o;
    o.x = f2bf(v.x); o.y = f2bf(v.y); o.z = f2bf(v.z); o.w = f2bf(v.w);
    ((ushort4*)out)[i] = o;
}

// GEMM1: qkv = x @ w_qkv^T (NT), 128x64 tile, BK=32, 16x16x32 MFMA.
// R14/R15 best-measured config: 4 waves x 32-row slices spanning 64 cols
// (IM=2, JN=4), depth-1 double buffer, 24 KB LDS, 6 blocks/CU, XCD swizzle,
// conflict-free (row>>1)&3 swizzle, vmcnt-carrying raw barriers.
// (R13 conflicts / R13+R16 prefetch-depth / R14 occupancy / R15 L2-locality
//  all individually falsified -- this config is the measured plateau.)
// Rotary+QSCALE fused on q/k col regions; V region (n0>=2048) written
// transposed+tau-permuted directly to Vt; qkv V third never written.
template <int SWXN>
__global__ __launch_bounds__(256, 6) void gemm1_qkv(const ushort_t* __restrict__ A,
                                                    const ushort_t* __restrict__ Bm,
                                                    const float* __restrict__ rot,
                                                    ushort_t* __restrict__ Vt,
                                                    ushort_t* __restrict__ Cout) {
    constexpr int K = DIMM;
    constexpr int NCH = 3;  // (512 A + 256 B chunks) / 256 threads
    __shared__ ushort_t As[2][128 * 32];
    __shared__ ushort_t Bs[2][64 * 32];
    const int t = threadIdx.x;
    const int lane = t & 63;
    const int w = t >> 6;
    const int quad = lane >> 4;
    const int l15 = lane & 15;
    const int blk = blockIdx.x;
    const int ii = blk >> 3;
    const int m0 = (ii / SWXN) * 128;
    const int n0 = ((blk & 7) * SWXN + ii % SWXN) * 64;
    const int wm = w * 32;

    float4v acc[2][4];
#pragma unroll
    for (int i = 0; i < 2; ++i)
#pragma unroll
        for (int j = 0; j < 4; ++j) acc[i][j] = (float4v)0.0f;

    int srow[NCH], slc[NCH], sdst[NCH];
    bool sisA[NCH];
#pragma unroll
    for (int u = 0; u < NCH; ++u) {
        int c = u * 256 + t;
        if (c < 512) {
            int row = c >> 2;
            sisA[u] = true; srow[u] = row; slc[u] = (c & 3) ^ ((row >> 1) & 3); sdst[u] = c * 8;
        } else {
            int cb = c - 512;
            int row = cb >> 2;
            sisA[u] = false; srow[u] = row; slc[u] = (cb & 3) ^ ((row >> 1) & 3); sdst[u] = cb * 8;
        }
    }
#pragma unroll
    for (int u = 0; u < NCH; ++u) {
        if (sisA[u]) gl2lds16(&A[(size_t)(m0 + srow[u]) * K + slc[u] * 8], &As[0][sdst[u]]);
        else         gl2lds16(&Bm[(size_t)(n0 + srow[u]) * K + slc[u] * 8], &Bs[0][sdst[u]]);
    }
    const int NIT = K >> 5;
    for (int it = 0; it < NIT; ++it) {
        const int cur = it & 1;
        if (it + 1 < NIT) {
            const int nxt = cur ^ 1;
            const int kc = (it + 1) << 5;
#pragma unroll
            for (int u = 0; u < NCH; ++u) {
                if (sisA[u]) gl2lds16(&A[(size_t)(m0 + srow[u]) * K + kc + slc[u] * 8], &As[nxt][sdst[u]]);
                else         gl2lds16(&Bm[(size_t)(n0 + srow[u]) * K + kc + slc[u] * 8], &Bs[nxt][sdst[u]]);
            }
            asm volatile("s_waitcnt vmcnt(3)\n\ts_barrier" ::: "memory");
        } else {
            asm volatile("s_waitcnt vmcnt(0)\n\ts_barrier" ::: "memory");
        }
        short8v a[2], b[4];
#pragma unroll
        for (int i = 0; i < 2; ++i) {
            int row = wm + i * 16 + l15;
            int pc = quad ^ ((row >> 1) & 3);
            a[i] = *(const short8v*)&As[cur][row * 32 + pc * 8];
        }
#pragma unroll
        for (int j = 0; j < 4; ++j) {
            int row = j * 16 + l15;
            int pc = quad ^ ((row >> 1) & 3);
            b[j] = *(const short8v*)&Bs[cur][row * 32 + pc * 8];
        }
#pragma unroll
        for (int i = 0; i < 2; ++i)
#pragma unroll
            for (int j = 0; j < 4; ++j)
                acc[i][j] = __builtin_amdgcn_mfma_f32_16x16x32_bf16(a[i], b[j], acc[i][j], 0, 0, 0);
        asm volatile("s_barrier" ::: "memory");
    }
    const int region = n0 >> 10;  // 0=q, 1=k, 2=v
    if (region == 2) {
        // V: write transposed + tau-permuted directly to Vt[b,h,dh,n'].
#pragma unroll
        for (int i = 0; i < 2; ++i) {
            int grow = m0 + wm + i * 16 + quad * 4;  // token, ==0 mod 4
            int bb = grow >> 11, nn_ = grow & (NN - 1);
            int tk = nn_ & 63;
            int tp = (tk & 32) | ((tk & 12) << 1) | ((tk & 16) >> 2);
            int nstore = (nn_ & ~63) | tp;  // j1=0; +r appends
#pragma unroll
            for (int j = 0; j < 4; ++j) {
                int vcol = n0 + j * 16 + l15 - 2048;
                int hh = vcol >> 6, dh = vcol & 63;
                uint2 st;
                st.x = pk_bf16(acc[i][j][0], acc[i][j][1]);
                st.y = pk_bf16(acc[i][j][2], acc[i][j][3]);
                *(uint2*)&Vt[((size_t)(bb * HH + hh) * DHH + dh) * NN + nstore] = st;
            }
        }
        return;
    }
    float scale = (region == 0) ? QSCALE : 1.0f;
#pragma unroll
    for (int i = 0; i < 2; ++i) {
#pragma unroll
        for (int r = 0; r < 4; ++r) {
            int n = (m0 + wm + i * 16 + quad * 4 + r) & (NN - 1);
#pragma unroll
            for (int jl = 0; jl < 2; ++jl) {
                int dh = jl * 16 + l15;
                float plo = rot[n * DHH + dh];
                float phi = rot[n * DHH + dh + 32];
                float lo = acc[i][jl][r], hi = acc[i][jl + 2][r];
                acc[i][jl][r]     = (lo * __cosf(plo) - hi * __sinf(plo)) * scale;
                acc[i][jl + 2][r] = (hi * __cosf(phi) + lo * __sinf(phi)) * scale;
            }
        }
    }
#pragma unroll
    for (int i = 0; i < 2; ++i) {
        int grow = m0 + wm + i * 16 + quad * 4;
#pragma unroll
        for (int j = 0; j < 4; ++j) {
            int gcol = n0 + j * 16 + l15;
#pragma unroll
            for (int r = 0; r < 4; ++r)
                Cout[(size_t)(grow + r) * QKV3 + gcol] = f2bf(acc[i][j][r]);
        }
    }
}

// GEMM2 with reduce_o FUSED into A-staging: y = [(po0+po1)/(l0+l1)] @ w_out^T + b.
// 64x64 tile, BK=32, 4 waves 2x2 (IM=2, JN=2). A-slab staged via register path:
// load po0/po1 uint4 + 2 lp floats -> normalize -> cvt_pk -> ds_write_b128
// (deletes the reduce_o dispatch and the 17 MB attn round-trip). B staged the
// same way (uniform sync). ONE lgkmcnt(0)+barrier per iteration: write-nxt /
// read-cur buffers never collide; the rendezvous seals prev-iter reads.
__global__ __launch_bounds__(256, 6) void gemm2_fused(const ushort_t* __restrict__ po,
                                                      const float* __restrict__ lp,
                                                      const ushort_t* __restrict__ Bm,
                                                      const float* __restrict__ bias,
                                                      float* __restrict__ y) {
    __shared__ ushort_t As[2][64 * 32];
    __shared__ ushort_t Bs[2][64 * 32];
    const int t = threadIdx.x;
    const int lane = t & 63;
    const int w = t >> 6;
    const int quad = lane >> 4;
    const int l15 = lane & 15;
    const int blk = blockIdx.x;  // 1024 = 8 XCD x (64 row-tiles x 2 col-tiles)
    const int ii = blk >> 3;
    const int m0 = (ii / 2) * 64;
    const int n0 = ((blk & 7) * 2 + ii % 2) * 64;
    const int wm = (w >> 1) * 32;
    const int wn = (w & 1) * 32;

    float4v acc[2][2];
#pragma unroll
    for (int i = 0; i < 2; ++i)
#pragma unroll
        for (int j = 0; j < 2; ++j) acc[i][j] = (float4v)0.0f;

    // per-thread chunk coords (one A chunk + one B chunk per slab)
    const int r = t >> 2;                      // row within 64-row slab
    const int slcA = (t & 3) ^ ((r >> 1) & 3); // logical 8-col group (swizzled)
    const int tok = m0 + r;
    const int bb = tok >> 11, nn_ = tok & (NN - 1);
    const size_t lpb = (size_t)(bb * 16) * NN + nn_;   // + h*NN per slab

    union U8 { uint4 v; unsigned u[4]; };
    U8 pa0, pa1, bw;
    float lv0, lv1;
    // prologue: load + convert slab 0 into buffer 0 (kc=0: h=0, dhbase=slcA*8)
    {
        size_t pbase = ((size_t)(bb * 16) * NN + nn_) * DHH + slcA * 8;
        pa0.v = *(const uint4*)&po[pbase];
        pa1.v = *(const uint4*)&po[pbase + (size_t)32 * NN * DHH];
        lv0 = lp[lpb];
        lv1 = lp[lpb + (size_t)32 * NN];
        bw.v = *(const uint4*)&Bm[(size_t)(n0 + r) * INNERR + slcA * 8];
        float inv = 1.0f / (lv0 + lv1);
        uint4 st;
#pragma unroll
        for (int q2 = 0; q2 < 4; ++q2) {
            float e0 = (bf2f(pa0.u[q2] & 0xffff) + bf2f(pa1.u[q2] & 0xffff)) * inv;
            float e1 = (bf2f(pa0.u[q2] >> 16)    + bf2f(pa1.u[q2] >> 16))    * inv;
            ((unsigned*)&st)[q2] = pk_bf16(e0, e1);
        }
        *(uint4*)&As[0][t * 8] = st;
        *(uint4*)&Bs[0][t * 8] = bw.v;
    }
    const int NIT = INNERR >> 5;  // 32
    for (int it = 0; it < NIT; ++it) {
        const int cur = it & 1;
        // my ds ops (incl. prev writes) complete + rendezvous: buf cur readable
        asm volatile("s_waitcnt lgkmcnt(0)\n\ts_barrier" ::: "memory");
        short8v a[2], b[2];
#pragma unroll
        for (int i = 0; i < 2; ++i) {
            int row = wm + i * 16 + l15;
            int pc = quad ^ ((row >> 1) & 3);
            a[i] = *(const short8v*)&As[cur][row * 32 + pc * 8];
        }
#pragma unroll
        for (int j = 0; j < 2; ++j) {
            int row = wn + j * 16 + l15;
            int pc = quad ^ ((row >> 1) & 3);
            b[j] = *(const short8v*)&Bs[cur][row * 32 + pc * 8];
        }
        if (it + 1 < NIT) {
            // issue next-slab loads early (compiler overlaps with MFMAs below)
            const int kc = (it + 1) << 5;
            const int h = kc >> 6;
            const int dh0 = (kc & 63 & 32) + slcA * 8;
            size_t pbase = ((size_t)(bb * 16 + h) * NN + nn_) * DHH + dh0;
            pa0.v = *(const uint4*)&po[pbase];
            pa1.v = *(const uint4*)&po[pbase + (size_t)32 * NN * DHH];
            lv0 = lp[lpb + (size_t)h * NN];
            lv1 = lp[lpb + (size_t)(32 + h) * NN];
            bw.v = *(const uint4*)&Bm[(size_t)(n0 + r) * INNERR + kc + slcA * 8];
        }
#pragma unroll
        for (int i = 0; i < 2; ++i)
#pragma unroll
            for (int j = 0; j < 2; ++j)
                acc[i][j] = __builtin_amdgcn_mfma_f32_16x16x32_bf16(a[i], b[j], acc[i][j], 0, 0, 0);
        if (it + 1 < NIT) {
            const int nxt = cur ^ 1;
            float inv = 1.0f / (lv0 + lv1);
            uint4 st;
#pragma unroll
            for (int q2 = 0; q2 < 4; ++q2) {
                float e0 = (bf2f(pa0.u[q2] & 0xffff) + bf2f(pa1.u[q2] & 0xffff)) * inv;
                float e1 = (bf2f(pa0.u[q2] >> 16)    + bf2f(pa1.u[q2] >> 16))    * inv;
                ((unsigned*)&st)[q2] = pk_bf16(e0, e1);
            }
            *(uint4*)&As[nxt][t * 8] = st;
            *(uint4*)&Bs[nxt][t * 8] = bw.v;
        }
    }
    // epilogue: bias + fp32 store
#pragma unroll
    for (int i = 0; i < 2; ++i) {
        int grow = m0 + wm + i * 16 + quad * 4;
#pragma unroll
        for (int j = 0; j < 2; ++j) {
            int gcol = n0 + wn + j * 16 + l15;
            float bv = bias[gcol];
#pragma unroll
            for (int rr = 0; rr < 4; ++rr)
                y[(size_t)(grow + rr) * INNERR + gcol] = acc[i][j][rr] + bv;
        }
    }
}

// MFMA flash attention, no-max exp2 softmax, S^T trick (P stays in registers),
// double-buffered K/V staging with raw-asm vmcnt-carrying barriers (R10 form).
// exp2 = bare v_exp_f32.
__global__ __launch_bounds__(256, 4) void flash_mfma(const ushort_t* __restrict__ qkv,
                                                     const ushort_t* __restrict__ Vt,
                                                     ushort_t* __restrict__ po,
                                                     float* __restrict__ lp) {
    __shared__ ushort_t smem[16384];  // 32 KB: Ks0|Ks1|Vts0|Vts1 (4096 each)
    ushort_t* Osc = smem;             // epilogue alias, safe after final barrier
    const int t = threadIdx.x;
    const int lane = t & 63;
    const int w = t >> 6;
    const int quad = lane >> 4;
    const int l15 = lane & 15;
    const int blk = blockIdx.x;  // 1024
    const int slot = blk >> 3;   // 128: ks(1) | qt(4) | bhh(2)
    const int ks = slot & 1;
    const int qt = (slot >> 1) & 15;
    const int bh = (blk & 7) * 4 + (slot >> 5);
    const int b = bh >> 4, h = bh & 15;
    const int n0 = qt * 128;

    short8v bq[2][2];
#pragma unroll
    for (int g = 0; g < 2; ++g) {
        size_t qb = (size_t)(b * NN + n0 + w * 32 + g * 16 + l15) * QKV3 + h * DHH + quad * 8;
        bq[g][0] = *(const short8v*)&qkv[qb];
        bq[g][1] = *(const short8v*)&qkv[qb + 32];
    }
    float4v o_acc[2][4];
    float4v l_acc[2];
#pragma unroll
    for (int g = 0; g < 2; ++g) {
        l_acc[g] = (float4v)0.0f;
#pragma unroll
        for (int nb = 0; nb < 4; ++nb) o_acc[g][nb] = (float4v)0.0f;
    }
    const short one_bf = (short)0x3F80;
    short8v ones8 = {one_bf, one_bf, one_bf, one_bf, one_bf, one_bf, one_bf, one_bf};

    const int s0 = t, s1 = 256 + t;
    const int r0 = s0 >> 3, lc0 = (s0 & 7) ^ (r0 & 7);
    const int r1 = s1 >> 3, lc1 = (s1 & 7) ^ (r1 & 7);
    const int koff0 = r0 * QKV3 + lc0 * 8, koff1 = r1 * QKV3 + lc1 * 8;
    const int voff0 = r0 * NN + lc0 * 8,   voff1 = r1 * NN + lc1 * 8;
    const ushort_t* kp = qkv + (size_t)b * NN * QKV3 + INNERR + h * DHH + (size_t)ks * 1024 * QKV3;
    const ushort_t* vp = Vt + (size_t)(b * HH + h) * DHH * NN + ks * 1024;

    {
        gl2lds16(kp + koff0, smem + 0 * 4096 + s0 * 8);
        gl2lds16(kp + koff1, smem + 0 * 4096 + s1 * 8);
        gl2lds16(vp + voff0, smem + 2 * 4096 + s0 * 8);
        gl2lds16(vp + voff1, smem + 2 * 4096 + s1 * 8);
    }
    for (int jt = 0; jt < 16; ++jt) {
        const int cur = jt & 1;
        if (jt < 15) {
            kp += 64 * QKV3;
            vp += 64;
            const int nxt = cur ^ 1;
            gl2lds16(kp + koff0, smem + nxt * 4096 + s0 * 8);
            gl2lds16(kp + koff1, smem + nxt * 4096 + s1 * 8);
            gl2lds16(vp + voff0, smem + (2 + nxt) * 4096 + s0 * 8);
            gl2lds16(vp + voff1, smem + (2 + nxt) * 4096 + s1 * 8);
            asm volatile("s_waitcnt vmcnt(4)\n\ts_barrier" ::: "memory");
        } else {
            asm volatile("s_waitcnt vmcnt(0)\n\ts_barrier" ::: "memory");
        }
        const ushort_t* Ksc = smem + cur * 4096;
        const ushort_t* Vtc = smem + (2 + cur) * 4096;
        float4v s_acc[2][4];
#pragma unroll
        for (int g = 0; g < 2; ++g)
#pragma unroll
            for (int nb = 0; nb < 4; ++nb) s_acc[g][nb] = (float4v)0.0f;
#pragma unroll
        for (int kb = 0; kb < 2; ++kb)
#pragma unroll
            for (int nb = 0; nb < 4; ++nb) {
                int row = nb * 16 + l15;
                int pc = (kb * 4 + quad) ^ (row & 7);
                short8v ak = *(const short8v*)&Ksc[row * 64 + pc * 8];
                s_acc[0][nb] = __builtin_amdgcn_mfma_f32_16x16x32_bf16(ak, bq[0][kb], s_acc[0][nb], 0, 0, 0);
                s_acc[1][nb] = __builtin_amdgcn_mfma_f32_16x16x32_bf16(ak, bq[1][kb], s_acc[1][nb], 0, 0, 0);
            }
#pragma unroll
        for (int g = 0; g < 2; ++g) {
            float p[4][4];
#pragma unroll
            for (int nb = 0; nb < 4; ++nb)
#pragma unroll
                for (int rr = 0; rr < 4; ++rr) p[nb][rr] = fast_exp2(s_acc[g][nb][rr]);
            uint4 u0, u1;
            u0.x = pk_bf16(p[0][0], p[0][1]); u0.y = pk_bf16(p[0][2], p[0][3]);
            u0.z = pk_bf16(p[1][0], p[1][1]); u0.w = pk_bf16(p[1][2], p[1][3]);
            u1.x = pk_bf16(p[2][0], p[2][1]); u1.y = pk_bf16(p[2][2], p[2][3]);
            u1.z = pk_bf16(p[3][0], p[3][1]); u1.w = pk_bf16(p[3][2], p[3][3]);
            short8v ap0 = __builtin_bit_cast(short8v, u0);
            short8v ap1 = __builtin_bit_cast(short8v, u1);
            l_acc[g] = __builtin_amdgcn_mfma_f32_16x16x32_bf16(ap0, ones8, l_acc[g], 0, 0, 0);
            l_acc[g] = __builtin_amdgcn_mfma_f32_16x16x32_bf16(ap1, ones8, l_acc[g], 0, 0, 0);
#pragma unroll
            for (int nb = 0; nb < 4; ++nb) {
                int row = nb * 16 + l15;
                int pc0 = quad ^ (row & 7);
                int pc1 = (4 + quad) ^ (row & 7);
                short8v bv0 = *(const short8v*)&Vtc[row * 64 + pc0 * 8];
                short8v bv1 = *(const short8v*)&Vtc[row * 64 + pc1 * 8];
                o_acc[g][nb] = __builtin_amdgcn_mfma_f32_16x16x32_bf16(ap0, bv0, o_acc[g][nb], 0, 0, 0);
                o_acc[g][nb] = __builtin_amdgcn_mfma_f32_16x16x32_bf16(ap1, bv1, o_acc[g][nb], 0, 0, 0);
            }
        }
        asm volatile("s_barrier" ::: "memory");
    }
#pragma unroll
    for (int g = 0; g < 2; ++g) {
        if (l15 == 0)
            *(float4*)&lp[(size_t)(ks * 32 + bh) * NN + n0 + w * 32 + g * 16 + quad * 4] =
                *(float4*)&l_acc[g];
    }
    ushort_t* osc = Osc + w * (32 * 68);
#pragma unroll
    for (int g = 0; g < 2; ++g)
#pragma unroll
        for (int nb = 0; nb < 4; ++nb)
#pragma unroll
            for (int rr = 0; rr < 4; ++rr)
                osc[(g * 16 + quad * 4 + rr) * 68 + nb * 16 + l15] = f2bf(o_acc[g][nb][rr]);
    __builtin_amdgcn_s_waitcnt(0);  // lgkmcnt(0): wave-private LDS ordering
    {
        int rr = lane >> 1, c0 = (lane & 1) * 32;
        size_t prow = ((size_t)(ks * 32 + bh) * NN + n0 + w * 32 + rr) * DHH + c0;
#pragma unroll
        for (int u = 0; u < 4; ++u) {
            uint4 v = *(const uint4*)&osc[rr * 68 + c0 + u * 8];
            *(uint4*)&po[prow + u * 8] = v;
        }
    }
}

extern "C" void kernel_launch(void* const* d_in, const int* in_sizes, int n_in,
                              void* d_out, int out_size, void* d_ws, size_t ws_size,
                              hipStream_t stream) {
    const float* x = (const float*)d_in[0];       // [2,2048,1024]
    const float* rot = (const float*)d_in[1];     // [2048,64]
    const float* w_qkv = (const float*)d_in[2];   // [3072,1024]
    const float* w_out = (const float*)d_in[3];   // [1024,1024]
    const float* b_out = (const float*)d_in[4];   // [1024]
    float* y = (float*)d_out;                     // [2,2048,1024] fp32

    char* ws = (char*)d_ws;
    ushort_t* qkv_bf  = (ushort_t*)(ws);               // 25,165,824 B (V third unused)
    ushort_t* vt_bf   = (ushort_t*)(ws + 25165824);    //  8,388,608 B [b,h,64,2048] (tau-permuted)
    ushort_t* wout_bf = (ushort_t*)(ws + 33554432);    //  2,097,152 B
    ushort_t* wqkv_bf = (ushort_t*)(ws + 35651584);    //  6,291,456 B (dead after GEMM1)
    float*    lp      = (float*)(ws + 35651584);       //    524,288 B (aliases wqkv_bf)
    ushort_t* x_bf    = (ushort_t*)(ws + 41943040);    //  8,388,608 B (dead after GEMM1)
    ushort_t* po      = (ushort_t*)(ws + 50331648);    // 16,777,216 B -> 64 MiB total

    conv_fused<<<8192, 256, 0, stream>>>(x, w_qkv, w_out, x_bf, wqkv_bf, wout_bf);
    // qkv = x @ w_qkv^T -> bf16 (q/k rotary-fused); V cols -> Vt directly.
    // 1536 blocks (6/CU), XCD-swizzled: 48 col-tiles = 8 XCDs x 6.
    gemm1_qkv<6><<<1536, 256, 0, stream>>>(x_bf, wqkv_bf, rot, vt_bf, qkv_bf);
    // flash attention, 2-way K-split -> partial O (bf16) + l (fp32)
    flash_mfma<<<1024, 256, 0, stream>>>(qkv_bf, vt_bf, po, lp);
    // y = normalize(po0+po1) @ w_out^T + b_out (reduce_o fused into staging)
    gemm2_fused<<<1024, 256, 0, stream>>>(po, lp, wout_bf, b_out, y);
}

// Round 18
// 202.856 us; speedup vs baseline: 1.0305x; 1.0305x over previous
//
#include <hip/hip_runtime.h>
#include <math.h>

typedef unsigned short ushort_t;
typedef __attribute__((ext_vector_type(8))) short short8v;
typedef __attribute__((ext_vector_type(4))) float float4v;

#define BB 2
#define NN 2048
#define HH 16
#define DHH 64
#define DIMM 1024
#define QKV3 3072
#define INNERR 1024
// 0.125 * log2(e): fold attention scale + base-2 exp into Q
#define QSCALE 0.1803368801111244f

__device__ __forceinline__ ushort_t f2bf(float f) {
    unsigned u = __float_as_uint(f);
    u += 0x7fffu + ((u >> 16) & 1u);  // round to nearest even
    return (ushort_t)(u >> 16);
}
__device__ __forceinline__ float bf2f(unsigned h) {
    return __uint_as_float(h << 16);
}
__device__ __forceinline__ unsigned pk_bf16(float a, float b) {
#if __has_builtin(__builtin_amdgcn_cvt_pk_bf16_f32)
    typedef __attribute__((ext_vector_type(2))) __bf16 bf16x2;
    bf16x2 r = __builtin_amdgcn_cvt_pk_bf16_f32(a, b);
    return __builtin_bit_cast(unsigned, r);
#else
    return (unsigned)f2bf(a) | ((unsigned)f2bf(b) << 16);
#endif
}
// bare v_exp_f32 -- OCML exp2f carries denorm/overflow guards we don't need
__device__ __forceinline__ float fast_exp2(float x) {
#if __has_builtin(__builtin_amdgcn_exp2f)
    return __builtin_amdgcn_exp2f(x);
#else
    return exp2f(x);
#endif
}
__device__ __forceinline__ void gl2lds16(const void* g, void* l) {
    __builtin_amdgcn_global_load_lds(
        (const __attribute__((address_space(1))) unsigned int*)g,
        (__attribute__((address_space(3))) unsigned int*)l, 16, 0, 0);
}

// One kernel converts x (4096 blks), w_qkv (3072), w_out (1024) to bf16.
__global__ __launch_bounds__(256) void conv_fused(const float* __restrict__ x,
                                                  const float* __restrict__ wqkv,
                                                  const float* __restrict__ wout,
                                                  ushort_t* __restrict__ xo,
                                                  ushort_t* __restrict__ wqkvo,
                                                  ushort_t* __restrict__ wouto) {
    int blk = blockIdx.x;
    const float* in; ushort_t* out; int i;
    if (blk < 4096)      { in = x;    out = xo;    i = blk * 256 + threadIdx.x; }
    else if (blk < 7168) { in = wqkv; out = wqkvo; i = (blk - 4096) * 256 + threadIdx.x; }
    else                 { in = wout; out = wouto; i = (blk - 7168) * 256 + threadIdx.x; }
    float4 v = ((const float4*)in)[i];
    ushort4 o;
    o.x = f2bf(v.x); o.y = f2bf(v.y); o.z = f2bf(v.z); o.w = f2bf(v.w);
    ((ushort4*)out)[i] = o;
}

// GEMM1: qkv = x @ w_qkv^T (NT), 128x64 tile, BK=32, 16x16x32 MFMA.
// Best-measured config (53.0 us, R17): 4 waves x 32-row slices spanning 64
// cols (IM=2, JN=4), depth-1 dbuf, 24 KB LDS, 6 blocks/CU, XCD swizzle,
// conflict-free (row>>1)&3 swizzle, vmcnt-carrying raw barriers.
// Rotary+QSCALE fused on q/k col regions; V region (n0>=2048) written
// transposed+tau-permuted directly to Vt; qkv V third never written.
template <int SWXN>
__global__ __launch_bounds__(256, 6) void gemm1_qkv(const ushort_t* __restrict__ A,
                                                    const ushort_t* __restrict__ Bm,
                                                    const float* __restrict__ rot,
                                                    ushort_t* __restrict__ Vt,
                                                    ushort_t* __restrict__ Cout) {
    constexpr int K = DIMM;
    constexpr int NCH = 3;  // (512 A + 256 B chunks) / 256 threads
    __shared__ ushort_t As[2][128 * 32];
    __shared__ ushort_t Bs[2][64 * 32];
    const int t = threadIdx.x;
    const int lane = t & 63;
    const int w = t >> 6;
    const int quad = lane >> 4;
    const int l15 = lane & 15;
    const int blk = blockIdx.x;
    const int ii = blk >> 3;
    const int m0 = (ii / SWXN) * 128;
    const int n0 = ((blk & 7) * SWXN + ii % SWXN) * 64;
    const int wm = w * 32;

    float4v acc[2][4];
#pragma unroll
    for (int i = 0; i < 2; ++i)
#pragma unroll
        for (int j = 0; j < 4; ++j) acc[i][j] = (float4v)0.0f;

    int srow[NCH], slc[NCH], sdst[NCH];
    bool sisA[NCH];
#pragma unroll
    for (int u = 0; u < NCH; ++u) {
        int c = u * 256 + t;
        if (c < 512) {
            int row = c >> 2;
            sisA[u] = true; srow[u] = row; slc[u] = (c & 3) ^ ((row >> 1) & 3); sdst[u] = c * 8;
        } else {
            int cb = c - 512;
            int row = cb >> 2;
            sisA[u] = false; srow[u] = row; slc[u] = (cb & 3) ^ ((row >> 1) & 3); sdst[u] = cb * 8;
        }
    }
#pragma unroll
    for (int u = 0; u < NCH; ++u) {
        if (sisA[u]) gl2lds16(&A[(size_t)(m0 + srow[u]) * K + slc[u] * 8], &As[0][sdst[u]]);
        else         gl2lds16(&Bm[(size_t)(n0 + srow[u]) * K + slc[u] * 8], &Bs[0][sdst[u]]);
    }
    const int NIT = K >> 5;
    for (int it = 0; it < NIT; ++it) {
        const int cur = it & 1;
        if (it + 1 < NIT) {
            const int nxt = cur ^ 1;
            const int kc = (it + 1) << 5;
#pragma unroll
            for (int u = 0; u < NCH; ++u) {
                if (sisA[u]) gl2lds16(&A[(size_t)(m0 + srow[u]) * K + kc + slc[u] * 8], &As[nxt][sdst[u]]);
                else         gl2lds16(&Bm[(size_t)(n0 + srow[u]) * K + kc + slc[u] * 8], &Bs[nxt][sdst[u]]);
            }
            asm volatile("s_waitcnt vmcnt(3)\n\ts_barrier" ::: "memory");
        } else {
            asm volatile("s_waitcnt vmcnt(0)\n\ts_barrier" ::: "memory");
        }
        short8v a[2], b[4];
#pragma unroll
        for (int i = 0; i < 2; ++i) {
            int row = wm + i * 16 + l15;
            int pc = quad ^ ((row >> 1) & 3);
            a[i] = *(const short8v*)&As[cur][row * 32 + pc * 8];
        }
#pragma unroll
        for (int j = 0; j < 4; ++j) {
            int row = j * 16 + l15;
            int pc = quad ^ ((row >> 1) & 3);
            b[j] = *(const short8v*)&Bs[cur][row * 32 + pc * 8];
        }
#pragma unroll
        for (int i = 0; i < 2; ++i)
#pragma unroll
            for (int j = 0; j < 4; ++j)
                acc[i][j] = __builtin_amdgcn_mfma_f32_16x16x32_bf16(a[i], b[j], acc[i][j], 0, 0, 0);
        asm volatile("s_barrier" ::: "memory");
    }
    const int region = n0 >> 10;  // 0=q, 1=k, 2=v
    if (region == 2) {
        // V: write transposed + tau-permuted directly to Vt[b,h,dh,n'].
#pragma unroll
        for (int i = 0; i < 2; ++i) {
            int grow = m0 + wm + i * 16 + quad * 4;  // token, ==0 mod 4
            int bb = grow >> 11, nn_ = grow & (NN - 1);
            int tk = nn_ & 63;
            int tp = (tk & 32) | ((tk & 12) << 1) | ((tk & 16) >> 2);
            int nstore = (nn_ & ~63) | tp;  // j1=0; +r appends
#pragma unroll
            for (int j = 0; j < 4; ++j) {
                int vcol = n0 + j * 16 + l15 - 2048;
                int hh = vcol >> 6, dh = vcol & 63;
                uint2 st;
                st.x = pk_bf16(acc[i][j][0], acc[i][j][1]);
                st.y = pk_bf16(acc[i][j][2], acc[i][j][3]);
                *(uint2*)&Vt[((size_t)(bb * HH + hh) * DHH + dh) * NN + nstore] = st;
            }
        }
        return;
    }
    float scale = (region == 0) ? QSCALE : 1.0f;
#pragma unroll
    for (int i = 0; i < 2; ++i) {
#pragma unroll
        for (int r = 0; r < 4; ++r) {
            int n = (m0 + wm + i * 16 + quad * 4 + r) & (NN - 1);
#pragma unroll
            for (int jl = 0; jl < 2; ++jl) {
                int dh = jl * 16 + l15;
                float plo = rot[n * DHH + dh];
                float phi = rot[n * DHH + dh + 32];
                float lo = acc[i][jl][r], hi = acc[i][jl + 2][r];
                acc[i][jl][r]     = (lo * __cosf(plo) - hi * __sinf(plo)) * scale;
                acc[i][jl + 2][r] = (hi * __cosf(phi) + lo * __sinf(phi)) * scale;
            }
        }
    }
#pragma unroll
    for (int i = 0; i < 2; ++i) {
        int grow = m0 + wm + i * 16 + quad * 4;
#pragma unroll
        for (int j = 0; j < 4; ++j) {
            int gcol = n0 + j * 16 + l15;
#pragma unroll
            for (int r = 0; r < 4; ++r)
                Cout[(size_t)(grow + r) * QKV3 + gcol] = f2bf(acc[i][j][r]);
        }
    }
}

// GEMM2 with reduce_o fused into A-staging, SOFTWARE-PIPELINED one full
// iteration deep (fixes R17's exposed register-load latency: loads were
// consumed ~40 cyc after issue; now they get a whole body+barrier of cover).
// Iter it: [lgkmcnt(0)+barrier] -> convert regs(slab it+1) -> write buf nxt
// -> issue loads(slab it+2) -> frag-read buf cur -> 4 MFMAs.
// Single register set: convert reads regs before reload (WAR via renaming).
__global__ __launch_bounds__(256, 6) void gemm2_fused(const ushort_t* __restrict__ po,
                                                      const float* __restrict__ lp,
                                                      const ushort_t* __restrict__ Bm,
                                                      const float* __restrict__ bias,
                                                      float* __restrict__ y) {
    __shared__ ushort_t As[2][64 * 32];
    __shared__ ushort_t Bs[2][64 * 32];
    const int t = threadIdx.x;
    const int lane = t & 63;
    const int w = t >> 6;
    const int quad = lane >> 4;
    const int l15 = lane & 15;
    const int blk = blockIdx.x;  // 1024 = 8 XCD x (64 row-tiles x 2 col-tiles)
    const int ii = blk >> 3;
    const int m0 = (ii / 2) * 64;
    const int n0 = ((blk & 7) * 2 + ii % 2) * 64;
    const int wm = (w >> 1) * 32;
    const int wn = (w & 1) * 32;

    float4v acc[2][2];
#pragma unroll
    for (int i = 0; i < 2; ++i)
#pragma unroll
        for (int j = 0; j < 2; ++j) acc[i][j] = (float4v)0.0f;

    const int r = t >> 2;                      // row within 64-row slab
    const int slcA = (t & 3) ^ ((r >> 1) & 3); // logical 8-col group (swizzled)
    const int tok = m0 + r;
    const int bb = tok >> 11, nn_ = tok & (NN - 1);
    const size_t lpb = (size_t)(bb * 16) * NN + nn_;

    union U8 { uint4 v; unsigned u[4]; };
    U8 pa0, pa1, bw;
    float lv0, lv1;

#define LOAD_SLAB(s)                                                            \
    {                                                                           \
        int h_ = (s) >> 1;                                                      \
        int dh0_ = (((s) & 1) << 5) + slcA * 8;                                 \
        size_t pbase_ = ((size_t)(bb * 16 + h_) * NN + nn_) * DHH + dh0_;       \
        pa0.v = *(const uint4*)&po[pbase_];                                     \
        pa1.v = *(const uint4*)&po[pbase_ + (size_t)32 * NN * DHH];             \
        lv0 = lp[lpb + (size_t)h_ * NN];                                        \
        lv1 = lp[lpb + (size_t)(32 + h_) * NN];                                 \
        bw.v = *(const uint4*)&Bm[(size_t)(n0 + r) * INNERR + ((s) << 5) + slcA * 8]; \
    }
#define STORE_SLAB(buf)                                                         \
    {                                                                           \
        float inv_ = 1.0f / (lv0 + lv1);                                        \
        uint4 st_;                                                              \
        _Pragma("unroll")                                                       \
        for (int q2 = 0; q2 < 4; ++q2) {                                        \
            float e0_ = (bf2f(pa0.u[q2] & 0xffff) + bf2f(pa1.u[q2] & 0xffff)) * inv_; \
            float e1_ = (bf2f(pa0.u[q2] >> 16)    + bf2f(pa1.u[q2] >> 16))    * inv_; \
            ((unsigned*)&st_)[q2] = pk_bf16(e0_, e1_);                          \
        }                                                                       \
        *(uint4*)&As[buf][t * 8] = st_;                                         \
        *(uint4*)&Bs[buf][t * 8] = bw.v;                                        \
    }

    // prologue: slab 0 -> buf 0; preload slab 1 regs
    LOAD_SLAB(0);
    STORE_SLAB(0);
    LOAD_SLAB(1);

    const int NIT = INNERR >> 5;  // 32
    for (int it = 0; it < NIT; ++it) {
        const int cur = it & 1;
        // my prev ds ops complete + rendezvous: buf cur readable by all,
        // buf cur^1 (reads sealed last iter) writable.
        asm volatile("s_waitcnt lgkmcnt(0)\n\ts_barrier" ::: "memory");
        if (it + 1 < NIT) STORE_SLAB(cur ^ 1);   // regs loaded a full iter ago
        if (it + 2 < NIT) LOAD_SLAB(it + 2);     // a full body+barrier of cover
        short8v a[2], b[2];
#pragma unroll
        for (int i = 0; i < 2; ++i) {
            int row = wm + i * 16 + l15;
            int pc = quad ^ ((row >> 1) & 3);
            a[i] = *(const short8v*)&As[cur][row * 32 + pc * 8];
        }
#pragma unroll
        for (int j = 0; j < 2; ++j) {
            int row = wn + j * 16 + l15;
            int pc = quad ^ ((row >> 1) & 3);
            b[j] = *(const short8v*)&Bs[cur][row * 32 + pc * 8];
        }
#pragma unroll
        for (int i = 0; i < 2; ++i)
#pragma unroll
            for (int j = 0; j < 2; ++j)
                acc[i][j] = __builtin_amdgcn_mfma_f32_16x16x32_bf16(a[i], b[j], acc[i][j], 0, 0, 0);
    }
#undef LOAD_SLAB
#undef STORE_SLAB
    // epilogue: bias + fp32 store
#pragma unroll
    for (int i = 0; i < 2; ++i) {
        int grow = m0 + wm + i * 16 + quad * 4;
#pragma unroll
        for (int j = 0; j < 2; ++j) {
            int gcol = n0 + wn + j * 16 + l15;
            float bv = bias[gcol];
#pragma unroll
            for (int rr = 0; rr < 4; ++rr)
                y[(size_t)(grow + rr) * INNERR + gcol] = acc[i][j][rr] + bv;
        }
    }
}

// MFMA flash attention, no-max exp2 softmax, S^T trick (P stays in registers),
// double-buffered K/V staging with raw-asm vmcnt-carrying barriers (R10 form).
// exp2 = bare v_exp_f32.
__global__ __launch_bounds__(256, 4) void flash_mfma(const ushort_t* __restrict__ qkv,
                                                     const ushort_t* __restrict__ Vt,
                                                     ushort_t* __restrict__ po,
                                                     float* __restrict__ lp) {
    __shared__ ushort_t smem[16384];  // 32 KB: Ks0|Ks1|Vts0|Vts1 (4096 each)
    ushort_t* Osc = smem;             // epilogue alias, safe after final barrier
    const int t = threadIdx.x;
    const int lane = t & 63;
    const int w = t >> 6;
    const int quad = lane >> 4;
    const int l15 = lane & 15;
    const int blk = blockIdx.x;  // 1024
    const int slot = blk >> 3;   // 128: ks(1) | qt(4) | bhh(2)
    const int ks = slot & 1;
    const int qt = (slot >> 1) & 15;
    const int bh = (blk & 7) * 4 + (slot >> 5);
    const int b = bh >> 4, h = bh & 15;
    const int n0 = qt * 128;

    short8v bq[2][2];
#pragma unroll
    for (int g = 0; g < 2; ++g) {
        size_t qb = (size_t)(b * NN + n0 + w * 32 + g * 16 + l15) * QKV3 + h * DHH + quad * 8;
        bq[g][0] = *(const short8v*)&qkv[qb];
        bq[g][1] = *(const short8v*)&qkv[qb + 32];
    }
    float4v o_acc[2][4];
    float4v l_acc[2];
#pragma unroll
    for (int g = 0; g < 2; ++g) {
        l_acc[g] = (float4v)0.0f;
#pragma unroll
        for (int nb = 0; nb < 4; ++nb) o_acc[g][nb] = (float4v)0.0f;
    }
    const short one_bf = (short)0x3F80;
    short8v ones8 = {one_bf, one_bf, one_bf, one_bf, one_bf, one_bf, one_bf, one_bf};

    const int s0 = t, s1 = 256 + t;
    const int r0 = s0 >> 3, lc0 = (s0 & 7) ^ (r0 & 7);
    const int r1 = s1 >> 3, lc1 = (s1 & 7) ^ (r1 & 7);
    const int koff0 = r0 * QKV3 + lc0 * 8, koff1 = r1 * QKV3 + lc1 * 8;
    const int voff0 = r0 * NN + lc0 * 8,   voff1 = r1 * NN + lc1 * 8;
    const ushort_t* kp = qkv + (size_t)b * NN * QKV3 + INNERR + h * DHH + (size_t)ks * 1024 * QKV3;
    const ushort_t* vp = Vt + (size_t)(b * HH + h) * DHH * NN + ks * 1024;

    {
        gl2lds16(kp + koff0, smem + 0 * 4096 + s0 * 8);
        gl2lds16(kp + koff1, smem + 0 * 4096 + s1 * 8);
        gl2lds16(vp + voff0, smem + 2 * 4096 + s0 * 8);
        gl2lds16(vp + voff1, smem + 2 * 4096 + s1 * 8);
    }
    for (int jt = 0; jt < 16; ++jt) {
        const int cur = jt & 1;
        if (jt < 15) {
            kp += 64 * QKV3;
            vp += 64;
            const int nxt = cur ^ 1;
            gl2lds16(kp + koff0, smem + nxt * 4096 + s0 * 8);
            gl2lds16(kp + koff1, smem + nxt * 4096 + s1 * 8);
            gl2lds16(vp + voff0, smem + (2 + nxt) * 4096 + s0 * 8);
            gl2lds16(vp + voff1, smem + (2 + nxt) * 4096 + s1 * 8);
            asm volatile("s_waitcnt vmcnt(4)\n\ts_barrier" ::: "memory");
        } else {
            asm volatile("s_waitcnt vmcnt(0)\n\ts_barrier" ::: "memory");
        }
        const ushort_t* Ksc = smem + cur * 4096;
        const ushort_t* Vtc = smem + (2 + cur) * 4096;
        float4v s_acc[2][4];
#pragma unroll
        for (int g = 0; g < 2; ++g)
#pragma unroll
            for (int nb = 0; nb < 4; ++nb) s_acc[g][nb] = (float4v)0.0f;
#pragma unroll
        for (int kb = 0; kb < 2; ++kb)
#pragma unroll
            for (int nb = 0; nb < 4; ++nb) {
                int row = nb * 16 + l15;
                int pc = (kb * 4 + quad) ^ (row & 7);
                short8v ak = *(const short8v*)&Ksc[row * 64 + pc * 8];
                s_acc[0][nb] = __builtin_amdgcn_mfma_f32_16x16x32_bf16(ak, bq[0][kb], s_acc[0][nb], 0, 0, 0);
                s_acc[1][nb] = __builtin_amdgcn_mfma_f32_16x16x32_bf16(ak, bq[1][kb], s_acc[1][nb], 0, 0, 0);
            }
#pragma unroll
        for (int g = 0; g < 2; ++g) {
            float p[4][4];
#pragma unroll
            for (int nb = 0; nb < 4; ++nb)
#pragma unroll
                for (int rr = 0; rr < 4; ++rr) p[nb][rr] = fast_exp2(s_acc[g][nb][rr]);
            uint4 u0, u1;
            u0.x = pk_bf16(p[0][0], p[0][1]); u0.y = pk_bf16(p[0][2], p[0][3]);
            u0.z = pk_bf16(p[1][0], p[1][1]); u0.w = pk_bf16(p[1][2], p[1][3]);
            u1.x = pk_bf16(p[2][0], p[2][1]); u1.y = pk_bf16(p[2][2], p[2][3]);
            u1.z = pk_bf16(p[3][0], p[3][1]); u1.w = pk_bf16(p[3][2], p[3][3]);
            short8v ap0 = __builtin_bit_cast(short8v, u0);
            short8v ap1 = __builtin_bit_cast(short8v, u1);
            l_acc[g] = __builtin_amdgcn_mfma_f32_16x16x32_bf16(ap0, ones8, l_acc[g], 0, 0, 0);
            l_acc[g] = __builtin_amdgcn_mfma_f32_16x16x32_bf16(ap1, ones8, l_acc[g], 0, 0, 0);
#pragma unroll
            for (int nb = 0; nb < 4; ++nb) {
                int row = nb * 16 + l15;
                int pc0 = quad ^ (row & 7);
                int pc1 = (4 + quad) ^ (row & 7);
                short8v bv0 = *(const short8v*)&Vtc[row * 64 + pc0 * 8];
                short8v bv1 = *(const short8v*)&Vtc[row * 64 + pc1 * 8];
                o_acc[g][nb] = __builtin_amdgcn_mfma_f32_16x16x32_bf16(ap0, bv0, o_acc[g][nb], 0, 0, 0);
                o_acc[g][nb] = __builtin_amdgcn_mfma_f32_16x16x32_bf16(ap1, bv1, o_acc[g][nb], 0, 0, 0);
            }
        }
        asm volatile("s_barrier" ::: "memory");
    }
#pragma unroll
    for (int g = 0; g < 2; ++g) {
        if (l15 == 0)
            *(float4*)&lp[(size_t)(ks * 32 + bh) * NN + n0 + w * 32 + g * 16 + quad * 4] =
                *(float4*)&l_acc[g];
    }
    ushort_t* osc = Osc + w * (32 * 68);
#pragma unroll
    for (int g = 0; g < 2; ++g)
#pragma unroll
        for (int nb = 0; nb < 4; ++nb)
#pragma unroll
            for (int rr = 0; rr < 4; ++rr)
                osc[(g * 16 + quad * 4 + rr) * 68 + nb * 16 + l15] = f2bf(o_acc[g][nb][rr]);
    __builtin_amdgcn_s_waitcnt(0);  // lgkmcnt(0): wave-private LDS ordering
    {
        int rr = lane >> 1, c0 = (lane & 1) * 32;
        size_t prow = ((size_t)(ks * 32 + bh) * NN + n0 + w * 32 + rr) * DHH + c0;
#pragma unroll
        for (int u = 0; u < 4; ++u) {
            uint4 v = *(const uint4*)&osc[rr * 68 + c0 + u * 8];
            *(uint4*)&po[prow + u * 8] = v;
        }
    }
}

extern "C" void kernel_launch(void* const* d_in, const int* in_sizes, int n_in,
                              void* d_out, int out_size, void* d_ws, size_t ws_size,
                              hipStream_t stream) {
    const float* x = (const float*)d_in[0];       // [2,2048,1024]
    const float* rot = (const float*)d_in[1];     // [2048,64]
    const float* w_qkv = (const float*)d_in[2];   // [3072,1024]
    const float* w_out = (const float*)d_in[3];   // [1024,1024]
    const float* b_out = (const float*)d_in[4];   // [1024]
    float* y = (float*)d_out;                     // [2,2048,1024] fp32

    char* ws = (char*)d_ws;
    ushort_t* qkv_bf  = (ushort_t*)(ws);               // 25,165,824 B (V third unused)
    ushort_t* vt_bf   = (ushort_t*)(ws + 25165824);    //  8,388,608 B [b,h,64,2048] (tau-permuted)
    ushort_t* wout_bf = (ushort_t*)(ws + 33554432);    //  2,097,152 B
    ushort_t* wqkv_bf = (ushort_t*)(ws + 35651584);    //  6,291,456 B (dead after GEMM1)
    float*    lp      = (float*)(ws + 35651584);       //    524,288 B (aliases wqkv_bf)
    ushort_t* x_bf    = (ushort_t*)(ws + 41943040);    //  8,388,608 B (dead after GEMM1)
    ushort_t* po      = (ushort_t*)(ws + 50331648);    // 16,777,216 B -> 64 MiB total

    conv_fused<<<8192, 256, 0, stream>>>(x, w_qkv, w_out, x_bf, wqkv_bf, wout_bf);
    // qkv = x @ w_qkv^T -> bf16 (q/k rotary-fused); V cols -> Vt directly.
    gemm1_qkv<6><<<1536, 256, 0, stream>>>(x_bf, wqkv_bf, rot, vt_bf, qkv_bf);
    // flash attention, 2-way K-split -> partial O (bf16) + l (fp32)
    flash_mfma<<<1024, 256, 0, stream>>>(qkv_bf, vt_bf, po, lp);
    // y = normalize(po0+po1) @ w_out^T + b_out (reduce_o fused, pipelined)
    gemm2_fused<<<1024, 256, 0, stream>>>(po, lp, wout_bf, b_out, y);
}